// Round 8
// baseline (70.318 us; speedup 1.0000x reference)
//
#include <hip/hip_runtime.h>

#define NB 16     // batch
#define CD 128    // channels
#define HW 4096   // spatial L
#define DD 512    // projected dim
#define KC 64     // clusters

typedef __attribute__((ext_vector_type(8))) short bfrag;           // 8 bf16 (4 VGPR)
typedef __attribute__((ext_vector_type(8))) unsigned short upk8;   // 8 bf16
typedef __attribute__((ext_vector_type(4))) float facc;            // MFMA acc
typedef __attribute__((ext_vector_type(4))) unsigned short upk4;   // 4 bf16

__device__ __forceinline__ unsigned short f2bf(float f) {
  union { float f; unsigned u; } v; v.f = f;
  unsigned r = v.u + 0x7fffu + ((v.u >> 16) & 1u);   // RNE
  return (unsigned short)(r >> 16);
}
__device__ __forceinline__ float bf2f(unsigned short h) {
  union { unsigned u; float f; } v; v.u = ((unsigned)h) << 16; return v.f;
}

// ---------- prep: centroid L2-normalize -> bf16 ; conv_w -> bf16 ----------
__global__ __launch_bounds__(256) void k_prep(const float* __restrict__ conv_w,
                                              const float* __restrict__ centroids,
                                              unsigned short* __restrict__ Wb,
                                              unsigned short* __restrict__ Cb) {
  int b = blockIdx.x, t = threadIdx.x;
  if (b < KC) {
    const float* row = centroids + (size_t)b * DD;
    float v0 = row[t], v1 = row[t + 256];
    float ss = v0 * v0 + v1 * v1;
    #pragma unroll
    for (int off = 32; off; off >>= 1) ss += __shfl_xor(ss, off);
    __shared__ float red[4];
    if ((t & 63) == 0) red[t >> 6] = ss;
    __syncthreads();
    float tot = red[0] + red[1] + red[2] + red[3];
    float inv = 1.0f / fmaxf(sqrtf(tot), 1e-12f);
    Cb[(size_t)b * DD + t]       = f2bf(v0 * inv);
    Cb[(size_t)b * DD + t + 256] = f2bf(v1 * inv);
  } else {
    int i = (b - KC) * 2048 + t * 8;            // 32 blocks cover 65536 elems
    const float4* src = (const float4*)(conv_w + i);
    float4 a = src[0], c = src[1];
    upk4 w0, w1;
    w0[0] = f2bf(a.x); w0[1] = f2bf(a.y); w0[2] = f2bf(a.z); w0[3] = f2bf(a.w);
    w1[0] = f2bf(c.x); w1[1] = f2bf(c.y); w1[2] = f2bf(c.z); w1[3] = f2bf(c.w);
    *(upk4*)(Wb + i)     = w0;
    *(upk4*)(Wb + i + 4) = w1;
  }
}

// ---------- fused xnorm + projection + logits/exp, 64l x (8 x 64d) tiles ----------
// LDS 40KB -> 4 blocks/CU.  Regions:
//   A [0,16K):  xt 128c x 128B | Ws 64d x 256B | fbuf 64l x 128B (8K) ; ps @8K (1K)
//   B [16K,32K): psum [8][64] (2K, read pre-Xn) | Xn 64l x 256B
//   C [32K,40K): Cbs 64k x 128B | etile 64k x 128B
__global__ __launch_bounds__(512, 8) void k_xproj(const float* __restrict__ x,
                                                  const unsigned short* __restrict__ Wb,
                                                  const unsigned short* __restrict__ Cb,
                                                  const float* __restrict__ conv_b,
                                                  unsigned short* __restrict__ fT,
                                                  unsigned short* __restrict__ e,
                                                  float* __restrict__ psums) {
  __shared__ __align__(16) char smem[40960];
  char* xt    = smem;                     // byte = c*128 + ((l*2) ^ ((c&15)<<3))
  char* Ws    = smem;                     // byte = d*256 + ((c*2) ^ ((d&7)<<4))
  char* fbuf  = smem;                     // byte = l*128 + ((dl*2) ^ ((l&7)<<4))
  float* ps   = (float*)(smem + 8192);    // [64][4]
  float* psum = (float*)(smem + 16384);   // [8][64]
  char* Xn    = smem + 16384;             // byte = l*256 + ((c*2) ^ ((l&7)<<4))
  char* Cbs   = smem + 32768;             // byte = k*128 + ((d*2) ^ ((k&7)<<4))
  char* etile = smem + 32768;             // byte = k*128 + ((l*2) ^ ((k&7)<<4))
  int n = blockIdx.y, l0 = blockIdx.x * 64;
  int t = threadIdx.x, lane = t & 63, wid = t >> 6;

  // P1: x (c, l0..l0+63) fp32 -> bf16 -> xt swizzled
  {
    int c = t >> 2;
    const float4* xrow = (const float4*)(x + ((size_t)n * CD + c) * HW + l0);
    int sw = (c & 15) << 3;
    #pragma unroll
    for (int j = 0; j < 4; j++) {
      int fq = (t & 3) + 4 * j;
      float4 v = xrow[fq];
      upk4 w;
      w[0] = f2bf(v.x); w[1] = f2bf(v.y); w[2] = f2bf(v.z); w[3] = f2bf(v.w);
      *(upk4*)(xt + c * 128 + ((fq * 8) ^ sw)) = w;
    }
  }
  __syncthreads();
  // P2: per-l sum of squares, 8 c-groups
  {
    int l = t & 63, g = t >> 6;
    float ss = 0.f;
    #pragma unroll
    for (int i = 0; i < 16; i++) {
      int c = g * 16 + i;
      float v = bf2f(*(const unsigned short*)(xt + c * 128 + ((l * 2) ^ ((c & 15) << 3))));
      ss += v * v;
    }
    psum[g * 64 + l] = ss;
  }
  __syncthreads();
  // P3: inv per l; transpose-normalize xt -> Xn
  {
    int l = t & 63, g = t >> 6;
    float tot = 0.f;
    #pragma unroll
    for (int gg = 0; gg < 8; gg++) tot += psum[gg * 64 + l];
    float inv = 1.0f / fmaxf(sqrtf(tot), 1e-12f);
    __syncthreads();                            // psum reads done before Xn writes
    #pragma unroll
    for (int h = 0; h < 2; h++) {
      int c0 = g * 16 + h * 8;
      upk8 w;
      #pragma unroll
      for (int i = 0; i < 8; i++) {
        int c = c0 + i;
        float v = bf2f(*(const unsigned short*)(xt + c * 128 + ((l * 2) ^ ((c & 15) << 3))));
        w[i] = f2bf(v * inv);
      }
      *(upk8*)(Xn + l * 256 + ((c0 * 2) ^ ((l & 7) << 4))) = w;
    }
  }

  // P4: 8 d-chunks of 64.  f wave grid 4(l)x2(d); e wave grid 2(k)x4(l).
  int wr = wid >> 1, wc = wid & 1;
  int er = wid >> 2, ec = wid & 3;
  int r0 = (lane >> 4) << 2, cl = lane & 15;
  facc zero = {0.f, 0.f, 0.f, 0.f};
  facc e_acc[2];
  e_acc[0] = zero; e_acc[1] = zero;

  for (int dch = 0; dch < 8; dch++) {
    __syncthreads();                            // (1) prev fbuf/Cbs reads (or P3 xt reads) done
    {   // stage Ws: Wb rows dch*64..+64, 256B each
      int d = t >> 3;
      const unsigned short* wrow = Wb + (size_t)(dch * 64 + d) * CD;
      int swd = (d & 7) << 4;
      #pragma unroll
      for (int j = 0; j < 2; j++) {
        int cc = (t & 7) + 8 * j;
        bfrag v = *(const bfrag*)(wrow + cc * 8);
        *(bfrag*)(Ws + d * 256 + ((cc * 16) ^ swd)) = v;
      }
    }
    {   // stage Cbs: Cb rows, d-range dch*64..+64 (128B per row)
      int k = t >> 3, c8 = t & 7;
      bfrag v = *(const bfrag*)(Cb + (size_t)k * DD + dch * 64 + c8 * 8);
      *(bfrag*)(Cbs + k * 128 + ((c8 * 16) ^ ((k & 7) << 4))) = v;
    }
    __syncthreads();                            // (2) staging visible
    // f-MFMA: 64l x 64d = Xn(64l x 128c) * Ws(64d x 128c)^T
    facc acc[2];
    acc[0] = zero; acc[1] = zero;
    #pragma unroll
    for (int kk = 0; kk < 128; kk += 32) {
      int c0 = kk + ((lane >> 4) << 3);
      int row = wr * 16 + (lane & 15);
      bfrag af = *(const bfrag*)(Xn + row * 256 + ((c0 * 2) ^ ((row & 7) << 4)));
      #pragma unroll
      for (int j = 0; j < 2; j++) {
        int drow = wc * 32 + j * 16 + (lane & 15);
        bfrag bf = *(const bfrag*)(Ws + drow * 256 + ((c0 * 2) ^ ((drow & 7) << 4)));
        acc[j] = __builtin_amdgcn_mfma_f32_16x16x32_bf16(af, bf, acc[j], 0, 0, 0);
      }
    }
    __syncthreads();                            // (3) Ws reads done; fbuf region free
    // epilogue: +bias -> fbuf (bf16, swizzled)
    {
      int lrow0 = wr * 16 + r0;
      #pragma unroll
      for (int j = 0; j < 2; j++) {
        int dloc = wc * 32 + j * 16 + cl;
        float bv = conv_b[dch * 64 + dloc];
        #pragma unroll
        for (int q = 0; q < 4; q++) {
          int lrow = lrow0 + q;
          *(unsigned short*)(fbuf + lrow * 128 + ((dloc * 2) ^ ((lrow & 7) << 4))) =
              f2bf(acc[j][q] + bv);
        }
      }
    }
    __syncthreads();                            // (4) fbuf complete
    // coalesced dump fbuf -> fT (store drain overlaps e-MFMA)
    {
      int l = t >> 3, cj = t & 7;
      bfrag v = *(const bfrag*)(fbuf + l * 128 + ((cj * 16) ^ ((l & 7) << 4)));
      *(bfrag*)(fT + ((size_t)n * HW + l0 + l) * DD + dch * 64 + cj * 8) = v;
    }
    // e-MFMA: e_acc += Cbs(64k x 64d) * fbuf(64l x 64d)^T
    #pragma unroll
    for (int kk = 0; kk < 64; kk += 32) {
      int d0 = kk + ((lane >> 4) << 3);
      int l2 = ec * 16 + (lane & 15);
      bfrag fb = *(const bfrag*)(fbuf + l2 * 128 + ((d0 * 2) ^ ((l2 & 7) << 4)));
      #pragma unroll
      for (int m2 = 0; m2 < 2; m2++) {
        int k2 = er * 32 + m2 * 16 + (lane & 15);
        bfrag ca = *(const bfrag*)(Cbs + k2 * 128 + ((d0 * 2) ^ ((k2 & 7) << 4)));
        e_acc[m2] = __builtin_amdgcn_mfma_f32_16x16x32_bf16(ca, fb, e_acc[m2], 0, 0, 0);
      }
    }
  }

  __syncthreads();                              // (5) fbuf/Cbs reads done -> etile/ps
  // P5: exp -> etile + rowsum partials -> ps
  {
    int l2 = ec * 16 + cl;
    #pragma unroll
    for (int m2 = 0; m2 < 2; m2++) {
      #pragma unroll
      for (int q = 0; q < 4; q++) {
        int k2 = er * 32 + m2 * 16 + r0 + q;
        float ev = __expf(e_acc[m2][q]);
        *(unsigned short*)(etile + k2 * 128 + ((l2 * 2) ^ ((k2 & 7) << 4))) = f2bf(ev);
        float v = ev;
        v += __shfl_xor(v, 1); v += __shfl_xor(v, 2);
        v += __shfl_xor(v, 4); v += __shfl_xor(v, 8);
        if (cl == 0) ps[k2 * 4 + ec] = v;
      }
    }
  }
  __syncthreads();                              // (6) etile + ps complete
  {   // coalesced dump etile -> e
    int k = t >> 3, cj = t & 7;
    bfrag v = *(const bfrag*)(etile + k * 128 + ((cj * 16) ^ ((k & 7) << 4)));
    *(bfrag*)(e + ((size_t)n * KC + k) * HW + l0 + cj * 8) = v;
  }
  if (t < 64)
    psums[((size_t)n * 64 + blockIdx.x) * 64 + t] =
        ps[t * 4] + ps[t * 4 + 1] + ps[t * 4 + 2] + ps[t * 4 + 3];
}

// ---------- rinv[n,k] = 1 / sum_tiles psums ----------
__global__ __launch_bounds__(256) void k_rinv(const float* __restrict__ psums,
                                              float* __restrict__ rinv) {
  int i = blockIdx.x * 256 + threadIdx.x;       // 1024 total
  int n = i >> 6, k = i & 63;
  float s = 0.f;
  for (int tn = 0; tn < 64; tn++) s += psums[((size_t)n * 64 + tn) * 64 + k];
  rinv[i] = 1.0f / s;
}

// ---------- vlad partials: part[sk,n,k,d] = sum_l e[n,k,l] f[n,l,d] ----------
// Grid 256 blocks, XCD-grouped so the 4 dt-blocks of one (n,sk) share an XCD.
__global__ __launch_bounds__(256) void k_vlad(const unsigned short* __restrict__ e,
                                              const unsigned short* __restrict__ fT,
                                              float* __restrict__ part) {
  __shared__ __align__(16) char smem[49152];
  char* As = smem;            // [64k][128l]: byte = k*256 + ((l*2)^((k&7)<<4))
  char* Bs = smem + 16384;    // [128d][128l]: byte = d*256 + ((l*2)^(((d&7)^((d>>3)&7))<<4))
  int t = threadIdx.x, lane = t & 63, wid = t >> 6;
  int wr = wid >> 1, wc = wid & 1;
  int lin = blockIdx.x;
  int xcd = lin & 7, jj = lin >> 3;
  int grp = xcd * 8 + (jj >> 2);                // 0..63 = (n,sk)
  int dt = jj & 3, n = grp >> 2, sk = grp & 3;
  int dbase = dt * 128;
  facc acc[2][4];
  facc zero = {0.f, 0.f, 0.f, 0.f};
  #pragma unroll
  for (int m = 0; m < 2; m++)
    #pragma unroll
    for (int j = 0; j < 4; j++) acc[m][j] = zero;

  for (int ks = 0; ks < 8; ks++) {
    int l0 = sk * 1024 + ks * 128;
    // stage A (e-tile 64k x 128l), swizzled b128 writes
    #pragma unroll
    for (int q = 0; q < 4; q++) {
      int ch = q * 256 + t;                      // k = ch>>4, lc = ch&15
      int k = ch >> 4, lc = ch & 15;
      bfrag v = *(const bfrag*)(e + ((size_t)n * KC + k) * HW + l0 + lc * 8);
      *(bfrag*)(As + k * 256 + ((lc * 16) ^ ((k & 7) << 4))) = v;
    }
    // stage B transposed (fT rows l -> Bs[d][l]), swizzled scalar writes
    #pragma unroll
    for (int q = 0; q < 8; q++) {
      int ch = q * 256 + t;                      // l = ch>>4, dc = ch&15
      int l = ch >> 4, dc = ch & 15;
      bfrag v = *(const bfrag*)(fT + ((size_t)n * HW + l0 + l) * DD + dbase + dc * 8);
      #pragma unroll
      for (int i = 0; i < 8; i++) {
        int d = dc * 8 + i;
        int swz = (((d & 7) ^ ((d >> 3) & 7)) << 4);
        *(unsigned short*)(Bs + d * 256 + ((l * 2) ^ swz)) = (unsigned short)v[i];
      }
    }
    __syncthreads();
    #pragma unroll
    for (int kk = 0; kk < 128; kk += 32) {
      int lk = kk + ((lane >> 4) << 3);
      bfrag af[2], bf[4];
      #pragma unroll
      for (int m = 0; m < 2; m++) {
        int krow = wr * 32 + m * 16 + (lane & 15);
        af[m] = *(const bfrag*)(As + krow * 256 + ((lk * 2) ^ ((krow & 7) << 4)));
      }
      #pragma unroll
      for (int j = 0; j < 4; j++) {
        int d = wc * 64 + j * 16 + (lane & 15);
        int swz = (((d & 7) ^ ((d >> 3) & 7)) << 4);
        bf[j] = *(const bfrag*)(Bs + d * 256 + ((lk * 2) ^ swz));
      }
      #pragma unroll
      for (int m = 0; m < 2; m++)
        #pragma unroll
        for (int j = 0; j < 4; j++)
          acc[m][j] = __builtin_amdgcn_mfma_f32_16x16x32_bf16(af[m], bf[j], acc[m][j], 0, 0, 0);
    }
    __syncthreads();
  }
  int r0 = (lane >> 4) << 2, cl = lane & 15;
  size_t base = ((size_t)(sk * NB + n)) * (KC * DD);
  #pragma unroll
  for (int m = 0; m < 2; m++) {
    int krow = wr * 32 + m * 16 + r0;
    #pragma unroll
    for (int j = 0; j < 4; j++) {
      int d = dbase + wc * 64 + j * 16 + cl;
      #pragma unroll
      for (int q = 0; q < 4; q++)
        part[base + (size_t)(krow + q) * DD + d] = acc[m][j][q];
    }
  }
}

// ---------- reduce split-K partials (4) and normalize by rinv ----------
__global__ __launch_bounds__(256) void k_reduce(const float* __restrict__ part,
                                                const float* __restrict__ rinv,
                                                float* __restrict__ out) {
  int i = blockIdx.x * 256 + threadIdx.x;
  float s = 0.f;
  #pragma unroll
  for (int skk = 0; skk < 4; skk++) s += part[(size_t)skk * (NB * KC * DD) + i];
  out[i] = s * rinv[i >> 9];                    // i>>9 = n*64+k
}

extern "C" void kernel_launch(void* const* d_in, const int* in_sizes, int n_in,
                              void* d_out, int out_size, void* d_ws, size_t ws_size,
                              hipStream_t stream) {
  const float* x         = (const float*)d_in[0];
  const float* conv_w    = (const float*)d_in[1];
  const float* conv_b    = (const float*)d_in[2];
  const float* centroids = (const float*)d_in[3];
  float* out = (float*)d_out;
  char* ws = (char*)d_ws;

  // ws layout (bytes):
  //   Wb    @ 0          (128 KB)   conv_w bf16 (D,C)
  //   Cb    @ 131072     (64 KB)    normalized centroids bf16 (K,D)
  //   fT    @ 196608     (64 MB)    f bf16 (N,L,D)
  //   e     @ 67305472   (8 MB)     exp(logits) bf16 (N,K,L)
  //   psums @ 75694080   (256 KB)   per-tile row sums fp32 (N,64,K)
  //   rinv  @ 75956224   (4 KB)     1/rowsum fp32 (N,K)
  //   part  @ 75960320   (8 MB)     vlad partials fp32 (4,N,K,D)
  unsigned short* Wb   = (unsigned short*)(ws);
  unsigned short* Cb   = (unsigned short*)(ws + 131072);
  unsigned short* fT   = (unsigned short*)(ws + 196608);
  unsigned short* ebuf = (unsigned short*)(ws + 67305472ull);
  float*          psums= (float*)(ws + 75694080ull);
  float*          rinv = (float*)(ws + 75956224ull);
  float*          part = (float*)(ws + 75960320ull);

  k_prep<<<dim3(96), dim3(256), 0, stream>>>(conv_w, centroids, Wb, Cb);

  // fused xnorm + projection + logits/exp -> fT, e, psums
  k_xproj<<<dim3(64, NB), dim3(512), 0, stream>>>(x, Wb, Cb, conv_b, fT, ebuf, psums);

  k_rinv<<<dim3(4), dim3(256), 0, stream>>>(psums, rinv);

  // vlad partials: e(K,L) * f(L,D), split-L into 4 chunks of 1024
  k_vlad<<<dim3(256), dim3(256), 0, stream>>>(ebuf, fT, part);

  k_reduce<<<dim3(NB * KC * DD / 256), dim3(256), 0, stream>>>(part, rinv, out);

  (void)in_sizes; (void)n_in; (void)out_size; (void)ws_size;
}